// Round 1
// baseline (723.299 us; speedup 1.0000x reference)
//
#include <hip/hip_runtime.h>
#include <hip/hip_bf16.h>

// logits[i] = sum_{(i,j) in E} Wt[j] + b ; out = log_softmax(logits, axis=1)
// N=100000, E=3200000, C=64.

__global__ void LINK_28991029248697_scatter(const int* __restrict__ ei,
                                            const float* __restrict__ Wt,
                                            float* __restrict__ logits,
                                            int E_) {
    int t = blockIdx.x * blockDim.x + threadIdx.x;   // E*64 = 204.8M < 2^31
    int e = t >> 6;
    int c = t & 63;
    if (e >= E_) return;
    int row = ei[e];          // edge_index[0][e]
    int col = ei[E_ + e];     // edge_index[1][e]
    atomicAdd(&logits[row * 64 + c], Wt[col * 64 + c]);
}

__global__ void LINK_28991029248697_logsoftmax(float* __restrict__ logits,
                                               const float* __restrict__ b,
                                               int N_) {
    int wave = (blockIdx.x * blockDim.x + threadIdx.x) >> 6;
    int c = threadIdx.x & 63;
    if (wave >= N_) return;

    float x = logits[wave * 64 + c] + b[c];

    // 64-lane max reduce
    float m = x;
    #pragma unroll
    for (int mask = 1; mask < 64; mask <<= 1) {
        float o = __shfl_xor(m, mask);
        m = fmaxf(m, o);
    }
    // 64-lane sum of exp(x - m)
    float s = __expf(x - m);
    #pragma unroll
    for (int mask = 1; mask < 64; mask <<= 1) {
        s += __shfl_xor(s, mask);
    }
    logits[wave * 64 + c] = x - m - logf(s);
}

extern "C" void kernel_launch(void* const* d_in, const int* in_sizes, int n_in,
                              void* d_out, int out_size, void* d_ws, size_t ws_size,
                              hipStream_t stream) {
    const int*   ei = (const int*)d_in[0];     // [2, E] int32
    const float* Wt = (const float*)d_in[1];   // [N, C] f32
    const float* b  = (const float*)d_in[2];   // [C] f32
    float* out = (float*)d_out;                // [N, C] f32

    const int E_ = in_sizes[0] / 2;
    const int C_ = in_sizes[2];
    const int N_ = in_sizes[1] / C_;

    hipMemsetAsync(d_out, 0, (size_t)N_ * C_ * sizeof(float), stream);

    {
        long long threads = (long long)E_ * 64;
        int block = 256;
        int grid = (int)((threads + block - 1) / block);
        LINK_28991029248697_scatter<<<grid, block, 0, stream>>>(ei, Wt, out, E_);
    }
    {
        int wavesPerBlock = 4;               // 256 threads
        int grid = (N_ + wavesPerBlock - 1) / wavesPerBlock;
        LINK_28991029248697_logsoftmax<<<grid, 256, 0, stream>>>(out, b, N_);
    }
}

// Round 2
// 706.689 us; speedup vs baseline: 1.0235x; 1.0235x over previous
//
#include <hip/hip_runtime.h>
#include <hip/hip_bf16.h>

// logits[i] = sum_{(i,j) in E} Wt[j] + b ; out = log_softmax(logits, axis=1)
// N=100000, E=3200000, C=64.
// Strategy: counting-sort edges by row into CSR, then one wave per node does
// coalesced register-accumulated gathers of Wt rows, fused with log-softmax.

#define CCH 64

__global__ void LINK_hist(const int* __restrict__ ei, int* __restrict__ counts, int E_) {
    int e = blockIdx.x * blockDim.x + threadIdx.x;
    if (e >= E_) return;
    atomicAdd(&counts[ei[e]], 1);
}

// Single-block hierarchical exclusive scan of counts[N] -> offsets[N+1], cursor[N]
__global__ void LINK_scan(const int* __restrict__ counts, int* __restrict__ offsets,
                          int* __restrict__ cursor, int N_) {
    __shared__ int part[1024];
    const int tid = threadIdx.x;
    const int chunk = (N_ + 1023) / 1024;
    const int beg = tid * chunk;
    const int end = min(beg + chunk, N_);
    int s = 0;
    for (int i = beg; i < end; ++i) s += counts[i];
    part[tid] = s;
    __syncthreads();
    // inclusive Hillis-Steele scan over 1024 partials
    for (int off = 1; off < 1024; off <<= 1) {
        int v = (tid >= off) ? part[tid - off] : 0;
        __syncthreads();
        part[tid] += v;
        __syncthreads();
    }
    int run = (tid == 0) ? 0 : part[tid - 1];   // exclusive prefix of my chunk
    for (int i = beg; i < end; ++i) {
        offsets[i] = run;
        cursor[i] = run;
        run += counts[i];
    }
    if (tid == 1023) offsets[N_] = run;          // == E (last thread's run = total)
}

__global__ void LINK_scatter_sort(const int* __restrict__ ei, int* __restrict__ cursor,
                                  int* __restrict__ scol, int E_) {
    int e = blockIdx.x * blockDim.x + threadIdx.x;
    if (e >= E_) return;
    int row = ei[e];
    int col = ei[E_ + e];
    int pos = atomicAdd(&cursor[row], 1);
    scol[pos] = col;
}

__global__ void LINK_gather_lsm(const int* __restrict__ offsets,
                                const int* __restrict__ scol,
                                const float* __restrict__ Wt,
                                const float* __restrict__ b,
                                float* __restrict__ out, int N_) {
    int wave = (blockIdx.x * blockDim.x + threadIdx.x) >> 6;
    int lane = threadIdx.x & 63;
    if (wave >= N_) return;

    int beg = offsets[wave];
    int end = offsets[wave + 1];

    float a0 = 0.f, a1 = 0.f, a2 = 0.f, a3 = 0.f;
    for (int base = beg; base < end; base += 64) {
        int myc = 0;
        if (base + lane < end) myc = scol[base + lane];   // coalesced col vector
        int iters = min(end - base, 64);
        int k = 0;
        for (; k + 4 <= iters; k += 4) {                  // 4 loads in flight
            int c0 = __shfl(myc, k);
            int c1 = __shfl(myc, k + 1);
            int c2 = __shfl(myc, k + 2);
            int c3 = __shfl(myc, k + 3);
            a0 += Wt[c0 * CCH + lane];
            a1 += Wt[c1 * CCH + lane];
            a2 += Wt[c2 * CCH + lane];
            a3 += Wt[c3 * CCH + lane];
        }
        for (; k < iters; ++k) {
            int c = __shfl(myc, k);
            a0 += Wt[c * CCH + lane];
        }
    }
    float x = (a0 + a1) + (a2 + a3) + b[lane];

    float m = x;
    #pragma unroll
    for (int mask = 1; mask < 64; mask <<= 1) m = fmaxf(m, __shfl_xor(m, mask));
    float s = __expf(x - m);
    #pragma unroll
    for (int mask = 1; mask < 64; mask <<= 1) s += __shfl_xor(s, mask);

    out[wave * CCH + lane] = x - m - logf(s);
}

// ---- fallback (round-1 atomic path) used only if ws too small ----
__global__ void LINK_scatter_atomic(const int* __restrict__ ei, const float* __restrict__ Wt,
                                    float* __restrict__ logits, int E_) {
    int t = blockIdx.x * blockDim.x + threadIdx.x;
    int e = t >> 6;
    int c = t & 63;
    if (e >= E_) return;
    atomicAdd(&logits[ei[e] * CCH + c], Wt[ei[E_ + e] * CCH + c]);
}
__global__ void LINK_lsm_inplace(float* __restrict__ logits, const float* __restrict__ b, int N_) {
    int wave = (blockIdx.x * blockDim.x + threadIdx.x) >> 6;
    int c = threadIdx.x & 63;
    if (wave >= N_) return;
    float x = logits[wave * CCH + c] + b[c];
    float m = x;
    #pragma unroll
    for (int mask = 1; mask < 64; mask <<= 1) m = fmaxf(m, __shfl_xor(m, mask));
    float s = __expf(x - m);
    #pragma unroll
    for (int mask = 1; mask < 64; mask <<= 1) s += __shfl_xor(s, mask);
    logits[wave * CCH + c] = x - m - logf(s);
}

extern "C" void kernel_launch(void* const* d_in, const int* in_sizes, int n_in,
                              void* d_out, int out_size, void* d_ws, size_t ws_size,
                              hipStream_t stream) {
    const int*   ei = (const int*)d_in[0];     // [2, E] int32
    const float* Wt = (const float*)d_in[1];   // [N, C] f32
    const float* b  = (const float*)d_in[2];   // [C] f32
    float* out = (float*)d_out;                // [N, C] f32

    const int E_ = in_sizes[0] / 2;
    const int C_ = in_sizes[2];
    const int N_ = in_sizes[1] / C_;

    // workspace layout (ints): counts[N] | offsets[N+1] | cursor[N] | pad | scol[E]
    size_t off_counts  = 0;
    size_t off_offsets = off_counts  + (size_t)N_ * 4;
    size_t off_cursor  = off_offsets + (size_t)(N_ + 1) * 4;
    size_t off_scol    = (off_cursor + (size_t)N_ * 4 + 255) & ~(size_t)255;
    size_t need        = off_scol + (size_t)E_ * 4;

    if (ws_size < need) {
        // fallback: atomic scatter (round-1 path)
        hipMemsetAsync(d_out, 0, (size_t)N_ * C_ * sizeof(float), stream);
        long long threads = (long long)E_ * 64;
        LINK_scatter_atomic<<<(int)((threads + 255) / 256), 256, 0, stream>>>(ei, Wt, out, E_);
        LINK_lsm_inplace<<<(N_ * 64 + 255) / 256, 256, 0, stream>>>(out, b, N_);
        return;
    }

    char* ws = (char*)d_ws;
    int* counts  = (int*)(ws + off_counts);
    int* offsets = (int*)(ws + off_offsets);
    int* cursor  = (int*)(ws + off_cursor);
    int* scol    = (int*)(ws + off_scol);

    hipMemsetAsync(counts, 0, (size_t)N_ * 4, stream);
    LINK_hist<<<(E_ + 255) / 256, 256, 0, stream>>>(ei, counts, E_);
    LINK_scan<<<1, 1024, 0, stream>>>(counts, offsets, cursor, N_);
    LINK_scatter_sort<<<(E_ + 255) / 256, 256, 0, stream>>>(ei, cursor, scol, E_);
    LINK_gather_lsm<<<(N_ * 64 + 255) / 256, 256, 0, stream>>>(offsets, scol, Wt, b, out, N_);
}